// Round 1
// baseline (3852.490 us; speedup 1.0000x reference)
//
#include <hip/hip_runtime.h>
#include <hip/hip_bf16.h>
#include <math.h>

// Problem constants (match reference)
#define B 256
#define N 2048
#define R 64
#define D 64
#define K 2
#define T 8
// derived
#define KD 128      // K*D, input width of layer 1
#define H2 128      // 2*D, hidden width

// One block per graph. 256 threads. Sequential loop over nodes R..N-1.
// d_out[b] is the live embeddings buffer: roots copied first, then each
// node's output written as it is produced; parent gathers read it back
// (same block -> __syncthreads() gives global-memory visibility).
__global__ __launch_bounds__(256)
void dag_encoder_kernel(const float* __restrict__ roots,   // [B,R,D]
                        const float* __restrict__ W1,      // [T,KD,H2]
                        const float* __restrict__ b1,      // [T,H2]
                        const float* __restrict__ W2,      // [T,H2,D]
                        const float* __restrict__ b2,      // [T,D]
                        const int*   __restrict__ idxs,    // [B,N,K]
                        const int*   __restrict__ types,   // [B,N]
                        float* __restrict__ out)           // [B,N,D]
{
    const int b   = blockIdx.x;
    const int tid = threadIdx.x;

    float* buf = out + (size_t)b * (N * D);

    // ---- copy roots into buf[0:R] (R*D = 4096 floats), vectorized ----
    {
        const float4* r4 = (const float4*)(roots + (size_t)b * (R * D));
        float4*       o4 = (float4*)buf;
        #pragma unroll
        for (int i = tid; i < (R * D) / 4; i += 256) o4[i] = r4[i];
    }
    __syncthreads();

    __shared__ float xs[KD];     // concatenated parent embeddings
    __shared__ float hs[H2];     // hidden activations
    __shared__ float part[256];  // partial-sum exchange

    const int* bidx = idxs  + (size_t)b * (N * K);
    const int* btyp = types + (size_t)b * N;

    const int j    = tid & 127;   // layer-1 output index
    const int half = tid >> 7;    // layer-1 i-range half (0/1)
    const int d    = tid & 63;    // layer-2 output index
    const int q    = tid >> 6;    // layer-2 j-range quarter (0..3)

    for (int pos = R; pos < N; ++pos) {
        const int typ = btyp[pos];
        const int i0  = bidx[pos * 2];
        const int i1  = bidx[pos * 2 + 1];

        // ---- gather parents: xs = concat(buf[i0], buf[i1]) ----
        if (tid < KD) {
            const int p = (tid < D) ? i0 : i1;
            xs[tid] = buf[p * D + (tid & (D - 1))];
        }
        __syncthreads();

        // ---- layer 1: 2 threads per output j, each dot over 64 i ----
        {
            const float* w  = W1 + typ * (KD * H2) + (half * 64) * H2 + j;
            const float* xx = xs + half * 64;
            float acc = 0.f;
            #pragma unroll
            for (int i = 0; i < 64; ++i) acc += xx[i] * w[i * H2];
            part[tid] = acc;
        }
        __syncthreads();
        if (tid < H2) {
            const float v = part[tid] + part[tid + 128] + b1[typ * H2 + tid];
            // exact GELU: 0.5*v*(1+erf(v/sqrt(2)))
            hs[tid] = 0.5f * v * (1.0f + erff(v * 0.70710678118654752f));
        }
        __syncthreads();

        // ---- layer 2: 4 threads per output d, each dot over 32 j ----
        {
            const float* w  = W2 + typ * (H2 * D) + (q * 32) * D + d;
            const float* hh = hs + q * 32;
            float acc = 0.f;
            #pragma unroll
            for (int jj = 0; jj < 32; ++jj) acc += hh[jj] * w[jj * D];
            part[tid] = acc;
        }
        __syncthreads();
        if (tid < D) {
            const float v = part[tid] + part[tid + 64] + part[tid + 128] +
                            part[tid + 192] + b2[typ * D + tid];
            buf[pos * D + tid] = v;
        }
        __syncthreads();  // make buf[pos] visible to next iteration's gather
    }
}

extern "C" void kernel_launch(void* const* d_in, const int* in_sizes, int n_in,
                              void* d_out, int out_size, void* d_ws, size_t ws_size,
                              hipStream_t stream) {
    const float* roots = (const float*)d_in[0];   // [B,R,D]
    const float* W1    = (const float*)d_in[1];   // [T,KD,H2]
    const float* b1    = (const float*)d_in[2];   // [T,H2]
    const float* W2    = (const float*)d_in[3];   // [T,H2,D]
    const float* b2    = (const float*)d_in[4];   // [T,D]
    const int*   idxs  = (const int*)d_in[5];     // [B,N,K]
    const int*   types = (const int*)d_in[6];     // [B,N]
    float*       out   = (float*)d_out;           // [B,N,D]

    dag_encoder_kernel<<<dim3(B), dim3(256), 0, stream>>>(
        roots, W1, b1, W2, b2, idxs, types, out);
}